// Round 3
// baseline (270.781 us; speedup 1.0000x reference)
//
#include <hip/hip_runtime.h>
#include <cstdint>
#include <cstddef>

#define DM 1024
#define NH 16
#define DQ 64
#define NB 8
#define LSEQ 1024

typedef __attribute__((ext_vector_type(8))) short short8;
typedef __attribute__((ext_vector_type(4))) float floatx4;

__device__ __forceinline__ unsigned short f2bf(float f) {
  union { float f; unsigned u; } v; v.f = f;
  unsigned r = v.u + 0x7FFFu + ((v.u >> 16) & 1u);
  return (unsigned short)(r >> 16);
}
__device__ __forceinline__ float bf2f(unsigned short u) {
  union { unsigned u; float f; } v; v.u = ((unsigned)u) << 16;
  return v.f;
}

__device__ __forceinline__ void async_load16(const void* g, void* l) {
  __builtin_amdgcn_global_load_lds(
      (const __attribute__((address_space(1))) unsigned int*)g,
      (__attribute__((address_space(3))) unsigned int*)l, 16, 0, 0);
}

// ---------------- convert q,k (f32 -> bf16) ----------------
__global__ void convert_qk(const float* __restrict__ q, const float* __restrict__ k,
                           unsigned short* __restrict__ qb, unsigned short* __restrict__ kb) {
  size_t i = ((size_t)blockIdx.x * 256 + threadIdx.x) * 4;
  float4 a = *(const float4*)&q[i];
  ushort4 r;
  r.x = f2bf(a.x); r.y = f2bf(a.y); r.z = f2bf(a.z); r.w = f2bf(a.w);
  *(ushort4*)&qb[i] = r;
  float4 b = *(const float4*)&k[i];
  ushort4 s;
  s.x = f2bf(b.x); s.y = f2bf(b.y); s.z = f2bf(b.z); s.w = f2bf(b.w);
  *(ushort4*)&kb[i] = s;
}

// ---------------- transpose W (f32 [K][N]) -> Wt (bf16 [N][K]) ----------------
__global__ void transpose_w(const float* __restrict__ Wq, const float* __restrict__ Wk,
                            const float* __restrict__ Wv, unsigned short* __restrict__ Wt) {
  int z = blockIdx.z;
  const float* W = (z == 0) ? Wq : (z == 1) ? Wk : Wv;
  __shared__ float tile[32][33];
  int n0 = blockIdx.x * 32, k0 = blockIdx.y * 32;
  int tx = threadIdx.x;
  for (int j = threadIdx.y; j < 32; j += 8)
    tile[j][tx] = W[(size_t)(k0 + j) * DM + n0 + tx];
  __syncthreads();
  unsigned short* o = Wt + (size_t)z * DM * DM;
  for (int j = threadIdx.y; j < 32; j += 8)
    o[(size_t)(n0 + j) * DM + k0 + tx] = f2bf(tile[tx][j]);
}

// ---------------- projection GEMM: 256x256 tile, 8-wave, 8-phase, DEPTH-2 prefetch ----------------
// BM=BN=256, BK=64. LDS 128 KiB: 2 buffers x {A-lo, A-hi, B-lo, B-hi} of 128x64 bf16.
// Iteration t computes tile t from buf(t&1) and stages ALL of tile t+2 into buf(t&1):
//   B region of buf(t&1) is dead after P2 (last LOAD_B), A region dead after P3 (last LOAD_A),
//   so B-lo(t+2) stages at P3, {B-hi,A-lo,A-hi}(t+2) at P4 — issue-to-wait window ~4-5 phases
//   (> HBM ~900cy latency), vs 2 phases in the previous rev (which stalled every iteration).
// vmcnt(8) at P4: 16 ops outstanding (tile t+1's 8 + tile t+2's 8) -> waits tile t+1 resident,
// leaves tile t+2 in flight. Never drains to 0 in the main loop (tail: t==14 drains).
#define HT0 0
#define HT1 8192
#define HT2 16384
#define HT3 24576

#define STAGE(REGB, SRCP, ROW0, KTV)                                      \
  {                                                                       \
    const unsigned short* sp_ = (SRCP) + (size_t)(ROW0) * DM + (KTV);     \
    async_load16(sp_, &smem[(REGB) + wave * 512]);                        \
    async_load16(sp_ + 64 * DM, &smem[(REGB) + 4096 + wave * 512]);       \
  }

#define LOAD_A(QA)                                                        \
  {                                                                       \
    _Pragma("unroll")                                                     \
    for (int i_ = 0; i_ < 4; ++i_) {                                      \
      const int ar_ = abase + ((QA) * 64 + i_ * 16 + l16) * 64;           \
      af[i_][0] = *(const short8*)&smem[ar_ + x0];                        \
      af[i_][1] = *(const short8*)&smem[ar_ + x1];                        \
    }                                                                     \
  }

#define LOAD_B(QB)                                                        \
  {                                                                       \
    _Pragma("unroll")                                                     \
    for (int j_ = 0; j_ < 2; ++j_) {                                      \
      const int br_ = bbase + ((QB) * 32 + j_ * 16 + l16) * 64;           \
      bqf[QB][j_][0] = *(const short8*)&smem[br_ + x0];                   \
      bqf[QB][j_][1] = *(const short8*)&smem[br_ + x1];                   \
    }                                                                     \
  }

#define PHASE_MFMA(RI, CI)                                                        \
  {                                                                               \
    __builtin_amdgcn_s_setprio(1);                                                \
    _Pragma("unroll")                                                             \
    for (int i_ = 0; i_ < 4; ++i_) {                                              \
      _Pragma("unroll")                                                           \
      for (int j_ = 0; j_ < 2; ++j_) {                                            \
        acc[(RI) + i_][(CI) + j_] = __builtin_amdgcn_mfma_f32_16x16x32_bf16(      \
            af[i_][0], bqf[(CI) >> 1][j_][0], acc[(RI) + i_][(CI) + j_], 0, 0, 0);\
        acc[(RI) + i_][(CI) + j_] = __builtin_amdgcn_mfma_f32_16x16x32_bf16(      \
            af[i_][1], bqf[(CI) >> 1][j_][1], acc[(RI) + i_][(CI) + j_], 0, 0, 0);\
      }                                                                           \
    }                                                                             \
    __builtin_amdgcn_s_setprio(0);                                                \
  }

__global__ __launch_bounds__(512, 2) void gemm_proj(
    const unsigned short* __restrict__ qbp, const unsigned short* __restrict__ kbp,
    const unsigned short* __restrict__ Wt,
    const float* __restrict__ bqv, const float* __restrict__ bkv, const float* __restrict__ bvv,
    unsigned short* __restrict__ Pq, unsigned short* __restrict__ Pk,
    unsigned short* __restrict__ Pvt,
    float* __restrict__ qmask, float* __restrict__ kmask) {
  const int z = blockIdx.z;
  const unsigned short* Asrc = (z == 0) ? qbp : kbp;
  const unsigned short* Bsrc = Wt + (size_t)z * DM * DM;
  const float* bias = (z == 0) ? bqv : (z == 1) ? bkv : bvv;

  __shared__ unsigned short smem[65536];  // 128 KiB: 2 x (A 256x64 + B 256x64)

  const int tid = threadIdx.x;
  const int lane = tid & 63;
  const int wave = tid >> 6;
  const int l16 = lane & 15, quad = lane >> 4;
  const int wm = wave >> 2, wn = wave & 3;  // 2M x 4N waves; per-wave C = 128x64
  const int rowBase = blockIdx.x * 256;
  const int colBase = blockIdx.y * 256;

  // staging: lane-constant source offset (pre-swizzled global address, linear LDS dest)
  const int srow = wave * 8 + (lane >> 3);
  const int scol = ((lane & 7) ^ (lane >> 3)) * 8;
  const unsigned short* Ap = Asrc + (size_t)srow * DM + scol;
  const unsigned short* Bp = Bsrc + (size_t)srow * DM + scol;
  // fragment-read swizzled chunk offsets (row&7 == l16&7 for all frag rows)
  const int x0 = (quad ^ (l16 & 7)) * 8;
  const int x1 = ((quad + 4) ^ (l16 & 7)) * 8;

  floatx4 acc[8][4];
  const floatx4 zf = {0.f, 0.f, 0.f, 0.f};
#pragma unroll
  for (int i = 0; i < 8; i++)
#pragma unroll
    for (int j = 0; j < 4; j++) acc[i][j] = zf;

  short8 af[4][2];        // current A-half frags (qa)
  short8 bqf[2][2][2];    // both B-half frags [qb][j][kk]

  // prologue: tile-0 (8 ops) into buf0, tile-1 (8 ops) into buf1.
  // vmcnt(8): tile-0 complete; tile-1 stays in flight (steady-state depth).
  STAGE(HT0, Ap, rowBase, 0);
  STAGE(HT1, Ap, rowBase + 128, 0);
  STAGE(HT2, Bp, colBase, 0);
  STAGE(HT3, Bp, colBase + 128, 0);
  STAGE(32768 + HT0, Ap, rowBase, 64);
  STAGE(32768 + HT1, Ap, rowBase + 128, 64);
  STAGE(32768 + HT2, Bp, colBase, 64);
  STAGE(32768 + HT3, Bp, colBase + 128, 64);
  asm volatile("s_waitcnt vmcnt(8)" ::: "memory");
  __builtin_amdgcn_s_barrier();

  for (int t = 0; t < 16; ++t) {
    const int bufb = (t & 1) << 15;
    const int abase = bufb + wm * 8192;
    const int bbase = bufb + HT2 + (wn >> 1) * 8192 + (wn & 1) * 4096;
    const int kt2 = (t + 2) * 64;

    // ---- P1: Q(0,0). reads A(qa0)+B(qb0)
    LOAD_A(0);
    LOAD_B(0);
    __builtin_amdgcn_s_barrier();
    asm volatile("s_waitcnt lgkmcnt(0)" ::: "memory");
    PHASE_MFMA(0, 0);
    __builtin_amdgcn_s_barrier();

    // ---- P2: Q(0,1). reads B(qb1) — last B read of this buffer
    LOAD_B(1);
    __builtin_amdgcn_s_barrier();
    asm volatile("s_waitcnt lgkmcnt(0)" ::: "memory");
    PHASE_MFMA(0, 2);
    __builtin_amdgcn_s_barrier();

    // ---- P3: Q(1,1). reads A(qa1) — last A read; stage B-lo(t+2) into freed B region
    LOAD_A(1);
    if (t < 14) STAGE(bufb + HT2, Bp, colBase, kt2);
    __builtin_amdgcn_s_barrier();
    asm volatile("s_waitcnt lgkmcnt(0)" ::: "memory");
    PHASE_MFMA(4, 2);
    __builtin_amdgcn_s_barrier();

    // ---- P4: Q(1,0). no ds_reads; stage B-hi + A-lo + A-hi of t+2; counted vmcnt(8)
    if (t < 14) {
      STAGE(bufb + HT3, Bp, colBase + 128, kt2);
      STAGE(bufb + HT0, Ap, rowBase, kt2);
      STAGE(bufb + HT1, Ap, rowBase + 128, kt2);
      asm volatile("s_waitcnt vmcnt(8)" ::: "memory");  // tile t+1 resident; tile t+2 in flight
    } else if (t == 14) {
      asm volatile("s_waitcnt vmcnt(0)" ::: "memory");  // drain tile-15
    }
    __builtin_amdgcn_s_barrier();
    PHASE_MFMA(4, 0);
    __builtin_amdgcn_s_barrier();
  }

  // ---- bias ----
#pragma unroll
  for (int ci = 0; ci < 4; ++ci) {
    const float bj = bias[colBase + wn * 64 + ci * 16 + l16];
#pragma unroll
    for (int ri = 0; ri < 8; ++ri)
#pragma unroll
      for (int r = 0; r < 4; ++r) acc[ri][ci][r] += bj;
  }

  if (z < 2) {
    float* mask = (z == 0) ? qmask : kmask;
    const int h = (colBase >> 6) + wn;
#pragma unroll
    for (int ri = 0; ri < 8; ++ri)
#pragma unroll
      for (int r = 0; r < 4; ++r) {
        float rs = acc[ri][0][r] + acc[ri][1][r] + acc[ri][2][r] + acc[ri][3][r];
        rs += __shfl_xor(rs, 1);
        rs += __shfl_xor(rs, 2);
        rs += __shfl_xor(rs, 4);
        rs += __shfl_xor(rs, 8);
        if (l16 == 0) {
          const int row = rowBase + wm * 128 + ri * 16 + quad * 4 + r;
          mask[((size_t)((row >> 10) * NH + h)) * LSEQ + (row & 1023)] = (rs != 0.f) ? 1.f : 0.f;
        }
      }
    unsigned short* P = (z == 0) ? Pq : Pk;
#pragma unroll
    for (int ci = 0; ci < 4; ++ci) {
      const int col = colBase + wn * 64 + ci * 16 + l16;
      const int hh = col >> 6, d = col & 63;
#pragma unroll
      for (int ri = 0; ri < 8; ++ri) {
        const int row0 = rowBase + wm * 128 + ri * 16 + quad * 4;
#pragma unroll
        for (int r = 0; r < 4; ++r) {
          const int rr = row0 + r;
          P[((size_t)((rr >> 10) * NH + hh) * LSEQ + (rr & 1023)) * DQ + d] = f2bf(acc[ri][ci][r]);
        }
      }
    }
  } else {
    // V-transpose epilogue: wave-private LDS slabs [64 cols][72], no cross-wave sync
    const int b = rowBase >> 10;
    const int l0r = rowBase & 1023;
    const int hh = (colBase >> 6) + wn;
    unsigned short* lds = &smem[wave * 4608];
    const size_t obase = ((size_t)(b * NH + hh) * DQ) * LSEQ + l0r + wm * 128;
    __builtin_amdgcn_s_barrier();  // main-loop LDS traffic fully retired
#pragma unroll
    for (int qa = 0; qa < 2; ++qa) {
#pragma unroll
      for (int i = 0; i < 4; ++i)
#pragma unroll
        for (int ci = 0; ci < 4; ++ci) {
          const int ri = qa * 4 + i;
          ushort4 v;
          v.x = f2bf(acc[ri][ci][0]); v.y = f2bf(acc[ri][ci][1]);
          v.z = f2bf(acc[ri][ci][2]); v.w = f2bf(acc[ri][ci][3]);
          *(ushort4*)&lds[(ci * 16 + l16) * 72 + i * 16 + quad * 4] = v;
        }
      asm volatile("s_waitcnt lgkmcnt(0)" ::: "memory");
#pragma unroll
      for (int ll = 0; ll < 8; ++ll) {
        const int idx = ll * 64 + lane;
        const int c = idx >> 3, seg = idx & 7;
        int4 v = *(const int4*)&lds[c * 72 + seg * 8];
        *(int4*)&Pvt[obase + qa * 64 + (size_t)c * LSEQ + seg * 8] = v;
      }
      if (qa == 0) asm volatile("s_waitcnt lgkmcnt(0)" ::: "memory");
    }
  }
}

// ---------------- flash attention v4: dbuf, XCD-local bh, heavy-qblk-first ----------------
__global__ __launch_bounds__(256, 4) void attn_kernel(
    const unsigned short* __restrict__ Q, const unsigned short* __restrict__ K,
    const unsigned short* __restrict__ Vt,  // [b][h][d][l]
    const float* __restrict__ kmask, const float* __restrict__ qmask,
    const float* __restrict__ qin, float* __restrict__ out) {
  const int bh = blockIdx.x;          // id%8 = bh%8 -> all qblks of a bh share an XCD
  const int qblk = 7 - blockIdx.y;    // heavy (long) q-blocks launch first -> better tail
  const int b = bh >> 4, h = bh & 15;
  const size_t base = (size_t)bh * LSEQ * DQ;

  const int tid = threadIdx.x;
  const int lane = tid & 63;
  const int wave = tid >> 6;
  const int l16 = lane & 15, quad = lane >> 4;
  const int qw = qblk * 128 + wave * 32;

  __shared__ unsigned short Ks[2 * 4096];
  __shared__ unsigned short Vs[2 * 4096];
  __shared__ unsigned short Ps[4][2304];

  short8 qf[2][2];
#pragma unroll
  for (int sub = 0; sub < 2; sub++)
#pragma unroll
    for (int c = 0; c < 2; c++) {
      short8 t = *(const short8*)&Q[base + (size_t)(qw + sub * 16 + l16) * DQ + c * 32 + quad * 8];
#pragma unroll
      for (int e = 0; e < 8; e++) t[e] = (short)f2bf(bf2f((unsigned short)t[e]) * 0.125f);
      qf[sub][c] = t;
    }

  const floatx4 zf = {0.f, 0.f, 0.f, 0.f};
  floatx4 o[2][4];
#pragma unroll
  for (int sub = 0; sub < 2; sub++)
#pragma unroll
    for (int jj = 0; jj < 4; jj++) o[sub][jj] = zf;
  float l_p[2][4] = {{0.f, 0.f, 0.f, 0.f}, {0.f, 0.f, 0.f, 0.f}};

  const int swz = (quad ^ (l16 & 7)) * 8;
  const int swz2 = ((quad + 4) ^ (l16 & 7)) * 8;
  const int vswz = (quad ^ (l16 >> 1)) * 8;
  const int vswz2 = ((quad + 4) ^ (l16 >> 1)) * 8;

  const int srl = (lane >> 3);
  const int ktiles = (qblk + 1) * 2;
  const int tmax = 2 * qblk + (wave >> 1);

  {
#pragma unroll
    for (int cc = wave; cc < 8; cc += 4) {
      const int rl = cc * 8 + srl;
      const int ck = ((lane & 7) ^ (rl & 7)) * 8;
      async_load16(&K[base + (size_t)rl * DQ + ck], &Ks[cc * 512]);
      const int cv = ((lane & 7) ^ ((rl >> 1) & 7)) * 8;
      async_load16(&Vt[base + (size_t)rl * LSEQ + cv], &Vs[cc * 512]);
    }
  }
  __syncthreads();

  for (int t = 0; t < ktiles; t++) {
    const int cur = t & 1;
    const int kt = t * 64;
    const bool live = (t <= tmax);

    float km[4];
    if (live) {
#pragma unroll
      for (int ct = 0; ct < 4; ct++) km[ct] = kmask[(size_t)bh * LSEQ + kt + ct * 16 + l16];
    }

    if (t + 1 < ktiles) {
      const int nkt = kt + 64;
      const int nb = (cur ^ 1) * 4096;
#pragma unroll
      for (int cc = wave; cc < 8; cc += 4) {
        const int rl = cc * 8 + srl;
        const int ck = ((lane & 7) ^ (rl & 7)) * 8;
        async_load16(&K[base + (size_t)(nkt + rl) * DQ + ck], &Ks[nb + cc * 512]);
        const int cv = ((lane & 7) ^ ((rl >> 1) & 7)) * 8;
        async_load16(&Vt[base + (size_t)rl * LSEQ + nkt + cv], &Vs[nb + cc * 512]);
      }
    }

    if (live) {
      const unsigned short* Kb = &Ks[cur * 4096];
      const unsigned short* Vb = &Vs[cur * 4096];
      const bool diag = (t == tmax);

#pragma unroll
      for (int sub = 0; sub < 2; sub++) {
        floatx4 s[4];
#pragma unroll
        for (int ct = 0; ct < 4; ct++) {
          const int kr = (ct * 16 + l16) * 64;
          const short8 kf0 = *(const short8*)&Kb[kr + swz];
          const short8 kf1 = *(const short8*)&Kb[kr + swz2];
          floatx4 sv = zf;
          sv = __builtin_amdgcn_mfma_f32_16x16x32_bf16(qf[sub][0], kf0, sv, 0, 0, 0);
          sv = __builtin_amdgcn_mfma_f32_16x16x32_bf16(qf[sub][1], kf1, sv, 0, 0, 0);
          s[ct] = sv;
        }
        const int row0 = qw + sub * 16 + quad * 4;
        unsigned short* pw = &Ps[wave][(sub * 16 + quad * 4) * 72];
        if (diag) {
#pragma unroll
          for (int ct = 0; ct < 4; ct++) {
            const int col = kt + ct * 16 + l16;
#pragma unroll
            for (int r = 0; r < 4; r++) {
              float e = __expf(s[ct][r]) * km[ct];
              e = (col <= row0 + r) ? e : 0.f;
              l_p[sub][r] += e;
              pw[r * 72 + ct * 16 + l16] = f2bf(e);
            }
          }
        } else {
#pragma unroll
          for (int ct = 0; ct < 4; ct++) {
#pragma unroll
            for (int r = 0; r < 4; r++) {
              float e = __expf(s[ct][r]) * km[ct];
              l_p[sub][r] += e;
              pw[r * 72 + ct * 16 + l16] = f2bf(e);
            }
          }
        }
      }
      asm volatile("s_waitcnt lgkmcnt(0)" ::: "memory");

      short8 pf[2][2];
#pragma unroll
      for (int sub = 0; sub < 2; sub++) {
        pf[sub][0] = *(const short8*)&Ps[wave][(sub * 16 + l16) * 72 + quad * 8];
        pf[sub][1] = *(const short8*)&Ps[wave][(sub * 16 + l16) * 72 + 32 + quad * 8];
      }
#pragma unroll
      for (int jj = 0; jj < 4; jj++) {
        const int vr = (jj * 16 + l16) * 64;
        const short8 vf0 = *(const short8*)&Vb[vr + vswz];
        const short8 vf1 = *(const short8*)&Vb[vr + vswz2];
#pragma unroll
        for (int sub = 0; sub < 2; sub++) {
          o[sub][jj] = __builtin_amdgcn_mfma_f32_16x16x32_bf16(pf[sub][0], vf0, o[sub][jj], 0, 0, 0);
          o[sub][jj] = __builtin_amdgcn_mfma_f32_16x16x32_bf16(pf[sub][1], vf1, o[sub][jj], 0, 0, 0);
        }
      }
    }
    __syncthreads();
  }

  const int hd = h * DQ;
#pragma unroll
  for (int sub = 0; sub < 2; sub++)
#pragma unroll
    for (int r = 0; r < 4; r++) {
      float lv = l_p[sub][r];
      lv += __shfl_xor(lv, 1);
      lv += __shfl_xor(lv, 2);
      lv += __shfl_xor(lv, 4);
      lv += __shfl_xor(lv, 8);
      const int row = qw + sub * 16 + quad * 4 + r;
      const float inv = qmask[(size_t)bh * LSEQ + row] / lv;
#pragma unroll
      for (int jj = 0; jj < 4; jj++) {
        const size_t oi = ((size_t)(b * LSEQ + row)) * DM + hd + jj * 16 + l16;
        out[oi] = o[sub][jj][r] * inv + qin[oi];
      }
    }
}

// ---------------- launch ----------------
extern "C" void kernel_launch(void* const* d_in, const int* in_sizes, int n_in,
                              void* d_out, int out_size, void* d_ws, size_t ws_size,
                              hipStream_t stream) {
  const float* q = (const float*)d_in[0];
  const float* k = (const float*)d_in[1];
  const float* Wq = (const float*)d_in[3];
  const float* bq = (const float*)d_in[4];
  const float* Wk = (const float*)d_in[5];
  const float* bk = (const float*)d_in[6];
  const float* Wv = (const float*)d_in[7];
  const float* bv = (const float*)d_in[8];
  float* out = (float*)d_out;

  char* w = (char*)d_ws;
  unsigned short* qb = (unsigned short*)(w + 0);
  unsigned short* kb = (unsigned short*)(w + 16777216);
  unsigned short* Wt = (unsigned short*)(w + 33554432);
  unsigned short* Pq = (unsigned short*)(w + 39845888);
  unsigned short* Pk = (unsigned short*)(w + 56623104);
  unsigned short* Pvt = (unsigned short*)(w + 73400320);
  float* qmask = (float*)(w + 90177536);
  float* kmask = (float*)(w + 90701824);

  convert_qk<<<8192, 256, 0, stream>>>(q, k, qb, kb);
  transpose_w<<<dim3(32, 32, 3), dim3(32, 8), 0, stream>>>(Wq, Wk, Wv, Wt);
  gemm_proj<<<dim3(32, 4, 3), 512, 0, stream>>>(qb, kb, Wt, bq, bk, bv,
                                                Pq, Pk, Pvt, qmask, kmask);
  attn_kernel<<<dim3(128, 8), 256, 0, stream>>>(Pq, Pk, Pvt, kmask, qmask, q, out);
}

// Round 4
// 253.849 us; speedup vs baseline: 1.0667x; 1.0667x over previous
//
#include <hip/hip_runtime.h>
#include <cstdint>
#include <cstddef>

#define DM 1024
#define NH 16
#define DQ 64
#define NB 8
#define LSEQ 1024

typedef __attribute__((ext_vector_type(8))) short short8;
typedef __attribute__((ext_vector_type(4))) float floatx4;

__device__ __forceinline__ unsigned short f2bf(float f) {
  union { float f; unsigned u; } v; v.f = f;
  unsigned r = v.u + 0x7FFFu + ((v.u >> 16) & 1u);
  return (unsigned short)(r >> 16);
}
__device__ __forceinline__ float bf2f(unsigned short u) {
  union { unsigned u; float f; } v; v.u = ((unsigned)u) << 16;
  return v.f;
}

__device__ __forceinline__ void async_load16(const void* g, void* l) {
  __builtin_amdgcn_global_load_lds(
      (const __attribute__((address_space(1))) unsigned int*)g,
      (__attribute__((address_space(3))) unsigned int*)l, 16, 0, 0);
}

// ---------------- convert q,k (f32 -> bf16) ----------------
__global__ void convert_qk(const float* __restrict__ q, const float* __restrict__ k,
                           unsigned short* __restrict__ qb, unsigned short* __restrict__ kb) {
  size_t i = ((size_t)blockIdx.x * 256 + threadIdx.x) * 4;
  float4 a = *(const float4*)&q[i];
  ushort4 r;
  r.x = f2bf(a.x); r.y = f2bf(a.y); r.z = f2bf(a.z); r.w = f2bf(a.w);
  *(ushort4*)&qb[i] = r;
  float4 b = *(const float4*)&k[i];
  ushort4 s;
  s.x = f2bf(b.x); s.y = f2bf(b.y); s.z = f2bf(b.z); s.w = f2bf(b.w);
  *(ushort4*)&kb[i] = s;
}

// ---------------- transpose W (f32 [K][N]) -> Wt (bf16 [N][K]) ----------------
__global__ void transpose_w(const float* __restrict__ Wq, const float* __restrict__ Wk,
                            const float* __restrict__ Wv, unsigned short* __restrict__ Wt) {
  int z = blockIdx.z;
  const float* W = (z == 0) ? Wq : (z == 1) ? Wk : Wv;
  __shared__ float tile[32][33];
  int n0 = blockIdx.x * 32, k0 = blockIdx.y * 32;
  int tx = threadIdx.x;
  for (int j = threadIdx.y; j < 32; j += 8)
    tile[j][tx] = W[(size_t)(k0 + j) * DM + n0 + tx];
  __syncthreads();
  unsigned short* o = Wt + (size_t)z * DM * DM;
  for (int j = threadIdx.y; j < 32; j += 8)
    o[(size_t)(n0 + j) * DM + k0 + tx] = f2bf(tile[tx][j]);
}

// ---------------- projection GEMM + fused masks + V-transpose epilogue ----------------
// grid (64 row, 8 col, 3): id%8 = row%8 -> all col-blocks of a row-strip share an XCD
// BK=64, XOR-swizzled chunk staging (2-way max on fragment b128 reads)
// Epilogue for z<2 rewritten: wave-private LDS transpose -> coalesced int4 stores
// (was: 128 scattered 2B stores/thread -> ~1.7x write amplification, WRITE_SIZE 83-90MB)
__global__ __launch_bounds__(256, 4) void gemm_proj(
    const unsigned short* __restrict__ qb, const unsigned short* __restrict__ kb,
    const unsigned short* __restrict__ Wt,
    const float* __restrict__ bq, const float* __restrict__ bk, const float* __restrict__ bv,
    const float* __restrict__ /*unused*/,
    unsigned short* __restrict__ Pq, unsigned short* __restrict__ Pk,
    unsigned short* __restrict__ Pvt,
    float* __restrict__ qmask, float* __restrict__ kmask) {
  const int z = blockIdx.z;
  const unsigned short* A = (z == 0) ? qb : kb;
  const unsigned short* Bt = Wt + (size_t)z * DM * DM;
  const float* bias = (z == 0) ? bq : (z == 1) ? bk : bv;

  __shared__ unsigned short smem[16384];  // As 128x64, Bs 128x64; epilogue reuses slabs
  unsigned short* As = smem;
  unsigned short* Bs = smem + 8192;

  const int tid = threadIdx.x;
  const int lane = tid & 63;
  const int wave = tid >> 6;
  const int l16 = lane & 15, quad = lane >> 4;
  const int wm = wave & 1, wn = wave >> 1;
  const int rowBase = blockIdx.x * 128;  // row on x -> XCD locality for A
  const int colBase = blockIdx.y * 128;

  floatx4 acc[4][4];
  const floatx4 zf = {0.f, 0.f, 0.f, 0.f};
#pragma unroll
  for (int i = 0; i < 4; i++)
#pragma unroll
    for (int j = 0; j < 4; j++) acc[i][j] = zf;

  const int srl = lane >> 3;
  const int sl7 = lane & 7;

  for (int kt = 0; kt < DM; kt += 64) {
#pragma unroll
    for (int cc = wave; cc < 16; cc += 4) {
      const int rl = cc * 8 + srl;
      const int ck = (sl7 ^ (rl & 7)) * 8;
      async_load16(A + (size_t)(rowBase + rl) * DM + kt + ck, &As[cc * 512]);
      async_load16(Bt + (size_t)(colBase + rl) * DM + kt + ck, &Bs[cc * 512]);
    }
    __syncthreads();

#pragma unroll
    for (int c = 0; c < 2; c++) {
      const int chnk = ((c << 2) + quad) ^ (l16 & 7);
      short8 af[4], bfr[4];
#pragma unroll
      for (int i = 0; i < 4; i++)
        af[i] = *(const short8*)&As[(wm * 64 + i * 16 + l16) * 64 + chnk * 8];
#pragma unroll
      for (int j = 0; j < 4; j++)
        bfr[j] = *(const short8*)&Bs[(wn * 64 + j * 16 + l16) * 64 + chnk * 8];
#pragma unroll
      for (int i = 0; i < 4; i++)
#pragma unroll
        for (int j = 0; j < 4; j++)
          acc[i][j] = __builtin_amdgcn_mfma_f32_16x16x32_bf16(af[i], bfr[j], acc[i][j], 0, 0, 0);
    }
    __syncthreads();
  }

#pragma unroll
  for (int j = 0; j < 4; j++) {
    const float bj = bias[colBase + wn * 64 + j * 16 + l16];
#pragma unroll
    for (int i = 0; i < 4; i++)
#pragma unroll
      for (int r = 0; r < 4; r++) acc[i][j][r] += bj;
  }

  if (z < 2) {
    float* mask = (z == 0) ? qmask : kmask;
    const int h = (colBase >> 6) + wn;
#pragma unroll
    for (int i = 0; i < 4; i++)
#pragma unroll
      for (int r = 0; r < 4; r++) {
        float rs = acc[i][0][r] + acc[i][1][r] + acc[i][2][r] + acc[i][3][r];
        rs += __shfl_xor(rs, 1);
        rs += __shfl_xor(rs, 2);
        rs += __shfl_xor(rs, 4);
        rs += __shfl_xor(rs, 8);
        if (l16 == 0) {
          const int row = rowBase + wm * 64 + i * 16 + quad * 4 + r;
          mask[((size_t)((row >> 10) * NH + h)) * LSEQ + (row & 1023)] = (rs != 0.f) ? 1.f : 0.f;
        }
      }
    // coalesced P write: wave-private LDS slab [32 rows][72], two passes.
    // wave's tile: rows rowBase+wm*64+(0..63)  (l = row&1023, batch fixed per block),
    // cols colBase+wn*64+(0..63) -> head h fixed per wave, d = j*16+l16 in [0,64).
    unsigned short* P = (z == 0) ? Pq : Pk;
    const int bb2 = rowBase >> 10;
    const int l0 = (rowBase & 1023) + wm * 64;
    const size_t pbase = ((size_t)(bb2 * NH + h) * LSEQ + l0) * DQ;
    unsigned short* lds = smem + wave * 2304;
#pragma unroll
    for (int pass = 0; pass < 2; ++pass) {
#pragma unroll
      for (int ii = 0; ii < 2; ++ii) {
        const int i = pass * 2 + ii;
#pragma unroll
        for (int j = 0; j < 4; ++j)
#pragma unroll
          for (int r = 0; r < 4; ++r)
            lds[(ii * 16 + quad * 4 + r) * 72 + j * 16 + l16] = f2bf(acc[i][j][r]);
      }
      asm volatile("s_waitcnt lgkmcnt(0)" ::: "memory");
#pragma unroll
      for (int ll = 0; ll < 4; ++ll) {
        const int c = ll * 8 + (lane >> 3);   // row within pass: 0..31
        const int seg = lane & 7;             // 16B segment within 128B row
        int4 v = *(const int4*)&lds[c * 72 + seg * 8];
        *(int4*)&P[pbase + (size_t)(pass * 32 + c) * DQ + seg * 8] = v;
      }
      if (pass == 0) asm volatile("s_waitcnt lgkmcnt(0)" ::: "memory");
    }
  } else {
    const int b = rowBase >> 10;
    const int l0r = rowBase & 1023;
#pragma unroll
    for (int j = 0; j < 4; j++) {
      __syncthreads();
#pragma unroll
      for (int i = 0; i < 4; i++) {
        ushort4 v;
        v.x = f2bf(acc[i][j][0]); v.y = f2bf(acc[i][j][1]);
        v.z = f2bf(acc[i][j][2]); v.w = f2bf(acc[i][j][3]);
        *(ushort4*)&smem[(wn * 16 + l16) * 136 + wm * 64 + i * 16 + quad * 4] = v;
      }
      __syncthreads();
      const int c = tid >> 3, seg = tid & 7;
      const int col = colBase + (c >> 4) * 64 + j * 16 + (c & 15);
      const int hh = col >> 6, d = col & 63;
      int4 t0 = *(const int4*)&smem[c * 136 + seg * 16];
      int4 t1 = *(const int4*)&smem[c * 136 + seg * 16 + 8];
      const size_t g = ((size_t)((b * NH + hh) * DQ + d)) * LSEQ + l0r + seg * 16;
      *(int4*)&Pvt[g] = t0;
      *(int4*)&Pvt[g + 8] = t1;
    }
  }
}

// ---------------- flash attention v4: dbuf, XCD-local bh, heavy-qblk-first ----------------
__global__ __launch_bounds__(256, 4) void attn_kernel(
    const unsigned short* __restrict__ Q, const unsigned short* __restrict__ K,
    const unsigned short* __restrict__ Vt,  // [b][h][d][l]
    const float* __restrict__ kmask, const float* __restrict__ qmask,
    const float* __restrict__ qin, float* __restrict__ out) {
  const int bh = blockIdx.x;          // id%8 = bh%8 -> all qblks of a bh share an XCD
  const int qblk = 7 - blockIdx.y;    // heavy (long) q-blocks launch first -> better tail
  const int b = bh >> 4, h = bh & 15;
  const size_t base = (size_t)bh * LSEQ * DQ;

  const int tid = threadIdx.x;
  const int lane = tid & 63;
  const int wave = tid >> 6;
  const int l16 = lane & 15, quad = lane >> 4;
  const int qw = qblk * 128 + wave * 32;

  __shared__ unsigned short Ks[2 * 4096];
  __shared__ unsigned short Vs[2 * 4096];
  __shared__ unsigned short Ps[4][2304];

  short8 qf[2][2];
#pragma unroll
  for (int sub = 0; sub < 2; sub++)
#pragma unroll
    for (int c = 0; c < 2; c++) {
      short8 t = *(const short8*)&Q[base + (size_t)(qw + sub * 16 + l16) * DQ + c * 32 + quad * 8];
#pragma unroll
      for (int e = 0; e < 8; e++) t[e] = (short)f2bf(bf2f((unsigned short)t[e]) * 0.125f);
      qf[sub][c] = t;
    }

  const floatx4 zf = {0.f, 0.f, 0.f, 0.f};
  floatx4 o[2][4];
#pragma unroll
  for (int sub = 0; sub < 2; sub++)
#pragma unroll
    for (int jj = 0; jj < 4; jj++) o[sub][jj] = zf;
  float l_p[2][4] = {{0.f, 0.f, 0.f, 0.f}, {0.f, 0.f, 0.f, 0.f}};

  const int swz = (quad ^ (l16 & 7)) * 8;
  const int swz2 = ((quad + 4) ^ (l16 & 7)) * 8;
  const int vswz = (quad ^ (l16 >> 1)) * 8;
  const int vswz2 = ((quad + 4) ^ (l16 >> 1)) * 8;

  const int srl = (lane >> 3);
  const int ktiles = (qblk + 1) * 2;
  const int tmax = 2 * qblk + (wave >> 1);

  {
#pragma unroll
    for (int cc = wave; cc < 8; cc += 4) {
      const int rl = cc * 8 + srl;
      const int ck = ((lane & 7) ^ (rl & 7)) * 8;
      async_load16(&K[base + (size_t)rl * DQ + ck], &Ks[cc * 512]);
      const int cv = ((lane & 7) ^ ((rl >> 1) & 7)) * 8;
      async_load16(&Vt[base + (size_t)rl * LSEQ + cv], &Vs[cc * 512]);
    }
  }
  __syncthreads();

  for (int t = 0; t < ktiles; t++) {
    const int cur = t & 1;
    const int kt = t * 64;
    const bool live = (t <= tmax);

    float km[4];
    if (live) {
#pragma unroll
      for (int ct = 0; ct < 4; ct++) km[ct] = kmask[(size_t)bh * LSEQ + kt + ct * 16 + l16];
    }

    if (t + 1 < ktiles) {
      const int nkt = kt + 64;
      const int nb = (cur ^ 1) * 4096;
#pragma unroll
      for (int cc = wave; cc < 8; cc += 4) {
        const int rl = cc * 8 + srl;
        const int ck = ((lane & 7) ^ (rl & 7)) * 8;
        async_load16(&K[base + (size_t)(nkt + rl) * DQ + ck], &Ks[nb + cc * 512]);
        const int cv = ((lane & 7) ^ ((rl >> 1) & 7)) * 8;
        async_load16(&Vt[base + (size_t)rl * LSEQ + nkt + cv], &Vs[nb + cc * 512]);
      }
    }

    if (live) {
      const unsigned short* Kb = &Ks[cur * 4096];
      const unsigned short* Vb = &Vs[cur * 4096];
      const bool diag = (t == tmax);

#pragma unroll
      for (int sub = 0; sub < 2; sub++) {
        floatx4 s[4];
#pragma unroll
        for (int ct = 0; ct < 4; ct++) {
          const int kr = (ct * 16 + l16) * 64;
          const short8 kf0 = *(const short8*)&Kb[kr + swz];
          const short8 kf1 = *(const short8*)&Kb[kr + swz2];
          floatx4 sv = zf;
          sv = __builtin_amdgcn_mfma_f32_16x16x32_bf16(qf[sub][0], kf0, sv, 0, 0, 0);
          sv = __builtin_amdgcn_mfma_f32_16x16x32_bf16(qf[sub][1], kf1, sv, 0, 0, 0);
          s[ct] = sv;
        }
        const int row0 = qw + sub * 16 + quad * 4;
        unsigned short* pw = &Ps[wave][(sub * 16 + quad * 4) * 72];
        if (diag) {
#pragma unroll
          for (int ct = 0; ct < 4; ct++) {
            const int col = kt + ct * 16 + l16;
#pragma unroll
            for (int r = 0; r < 4; r++) {
              float e = __expf(s[ct][r]) * km[ct];
              e = (col <= row0 + r) ? e : 0.f;
              l_p[sub][r] += e;
              pw[r * 72 + ct * 16 + l16] = f2bf(e);
            }
          }
        } else {
#pragma unroll
          for (int ct = 0; ct < 4; ct++) {
#pragma unroll
            for (int r = 0; r < 4; r++) {
              float e = __expf(s[ct][r]) * km[ct];
              l_p[sub][r] += e;
              pw[r * 72 + ct * 16 + l16] = f2bf(e);
            }
          }
        }
      }
      asm volatile("s_waitcnt lgkmcnt(0)" ::: "memory");

      short8 pf[2][2];
#pragma unroll
      for (int sub = 0; sub < 2; sub++) {
        pf[sub][0] = *(const short8*)&Ps[wave][(sub * 16 + l16) * 72 + quad * 8];
        pf[sub][1] = *(const short8*)&Ps[wave][(sub * 16 + l16) * 72 + 32 + quad * 8];
      }
#pragma unroll
      for (int jj = 0; jj < 4; jj++) {
        const int vr = (jj * 16 + l16) * 64;
        const short8 vf0 = *(const short8*)&Vb[vr + vswz];
        const short8 vf1 = *(const short8*)&Vb[vr + vswz2];
#pragma unroll
        for (int sub = 0; sub < 2; sub++) {
          o[sub][jj] = __builtin_amdgcn_mfma_f32_16x16x32_bf16(pf[sub][0], vf0, o[sub][jj], 0, 0, 0);
          o[sub][jj] = __builtin_amdgcn_mfma_f32_16x16x32_bf16(pf[sub][1], vf1, o[sub][jj], 0, 0, 0);
        }
      }
    }
    __syncthreads();
  }

  const int hd = h * DQ;
#pragma unroll
  for (int sub = 0; sub < 2; sub++)
#pragma unroll
    for (int r = 0; r < 4; r++) {
      float lv = l_p[sub][r];
      lv += __shfl_xor(lv, 1);
      lv += __shfl_xor(lv, 2);
      lv += __shfl_xor(lv, 4);
      lv += __shfl_xor(lv, 8);
      const int row = qw + sub * 16 + quad * 4 + r;
      const float inv = qmask[(size_t)bh * LSEQ + row] / lv;
#pragma unroll
      for (int jj = 0; jj < 4; jj++) {
        const size_t oi = ((size_t)(b * LSEQ + row)) * DM + hd + jj * 16 + l16;
        out[oi] = o[sub][jj][r] * inv + qin[oi];
      }
    }
}

// ---------------- launch ----------------
extern "C" void kernel_launch(void* const* d_in, const int* in_sizes, int n_in,
                              void* d_out, int out_size, void* d_ws, size_t ws_size,
                              hipStream_t stream) {
  const float* q = (const float*)d_in[0];
  const float* k = (const float*)d_in[1];
  const float* Wq = (const float*)d_in[3];
  const float* bq = (const float*)d_in[4];
  const float* Wk = (const float*)d_in[5];
  const float* bk = (const float*)d_in[6];
  const float* Wv = (const float*)d_in[7];
  const float* bv = (const float*)d_in[8];
  float* out = (float*)d_out;

  char* w = (char*)d_ws;
  unsigned short* qb = (unsigned short*)(w + 0);
  unsigned short* kb = (unsigned short*)(w + 16777216);
  unsigned short* Wt = (unsigned short*)(w + 33554432);
  unsigned short* Pq = (unsigned short*)(w + 39845888);
  unsigned short* Pk = (unsigned short*)(w + 56623104);
  unsigned short* Pvt = (unsigned short*)(w + 73400320);
  float* qmask = (float*)(w + 90177536);
  float* kmask = (float*)(w + 90701824);

  convert_qk<<<8192, 256, 0, stream>>>(q, k, qb, kb);
  transpose_w<<<dim3(32, 32, 3), dim3(32, 8), 0, stream>>>(Wq, Wk, Wv, Wt);
  gemm_proj<<<dim3(64, 8, 3), 256, 0, stream>>>(qb, kb, Wt, bq, bk, bv, nullptr,
                                                Pq, Pk, Pvt, qmask, kmask);
  attn_kernel<<<dim3(128, 8), 256, 0, stream>>>(Pq, Pk, Pvt, kmask, qmask, q, out);
}